// Round 10
// baseline (345.123 us; speedup 1.0000x reference)
//
#include <hip/hip_runtime.h>
#include <hip/hip_bf16.h>

// Problem constants
constexpr int B_    = 2;
constexpr int NTOK  = 2048;   // T*F per batch
constexpr int D_    = 1024;
constexpr int H_    = 16;
constexpr int E_    = 64;     // head dim

using bf16_t = __bf16;
using bf16x8 = __attribute__((ext_vector_type(8))) __bf16;
using bf16x4 = __attribute__((ext_vector_type(4))) __bf16;
using f32x4  = __attribute__((ext_vector_type(4))) float;
using s16x4  = __attribute__((ext_vector_type(4))) short;

#define NEG_BIG  (-30000.0f)          // finite mask sentinel (exp2 -> 0, never NaN)
#define QSCALE   (0.125f * 1.44269504088896f)   // 1/sqrt(64) * log2(e): exp2-domain softmax

// K=16 bf16 MFMA (carried-forward shape; two builtin naming conventions)
#if __has_builtin(__builtin_amdgcn_mfma_f32_16x16x16_bf16)
__device__ __forceinline__ f32x4 mfma16(bf16x4 a, bf16x4 b, f32x4 c) {
  return __builtin_amdgcn_mfma_f32_16x16x16_bf16(a, b, c, 0, 0, 0);
}
#else
__device__ __forceinline__ f32x4 mfma16(bf16x4 a, bf16x4 b, f32x4 c) {
  return __builtin_amdgcn_mfma_f32_16x16x16bf16_1k(
      __builtin_bit_cast(s16x4, a), __builtin_bit_cast(s16x4, b), c, 0, 0, 0);
}
#endif

// ---- async global->LDS 16B. LDS dest = wave-uniform base + lane*16.
__device__ __forceinline__ void load16_to_lds(const void* g, void* l) {
  __builtin_amdgcn_global_load_lds((const __attribute__((address_space(1))) void*)g,
                                   (__attribute__((address_space(3))) void*)l, 16, 0, 0);
}

// Stage 64x64 bf16 tile into LDS [64][64] with per-row XOR column-chunk swizzle.
__device__ __forceinline__ void stage64_async(const bf16_t* __restrict__ g, int gs,
                                              bf16_t* l, int tid) {
#pragma unroll
  for (int j = 0; j < 2; ++j) {
    int chunk = j * 256 + tid;            // 0..511, 16B each
    int row = chunk >> 3, cc = chunk & 7;
    int gcc = cc ^ (row & 7);
    load16_to_lds(g + (long)row * gs + gcc * 8, l + chunk * 8);
  }
}

// Stage 128x64 bf16 tile, same swizzle
__device__ __forceinline__ void stage128x64_async(const bf16_t* __restrict__ g, int gs,
                                                  bf16_t* l, int tid) {
#pragma unroll
  for (int j = 0; j < 4; ++j) {
    int chunk = j * 256 + tid;            // 0..1023
    int row = chunk >> 3, cc = chunk & 7;
    int gcc = cc ^ (row & 7);
    load16_to_lds(g + (long)row * gs + gcc * 8, l + chunk * 8);
  }
}

// Read an 8-elem MFMA fragment (global colchunk = ks*4+half) from swizzled LDS tile
__device__ __forceinline__ bf16x8 frag_ld(const bf16_t* l, int row, int ks, int half) {
  int cc = (ks * 4 + half) ^ (row & 7);
  return *(const bf16x8*)&l[row * 64 + cc * 8];
}

__device__ __forceinline__ bf16x8 cvt8(f32x4 f0, f32x4 f1) {
  bf16x8 v;
  v[0] = (bf16_t)f0[0]; v[1] = (bf16_t)f0[1]; v[2] = (bf16_t)f0[2]; v[3] = (bf16_t)f0[3];
  v[4] = (bf16_t)f1[0]; v[5] = (bf16_t)f1[1]; v[6] = (bf16_t)f1[2]; v[7] = (bf16_t)f1[3];
  return v;
}

__device__ __forceinline__ bf16x4 cvt4(f32x4 f, float sc) {
  bf16x4 v;
  v[0] = (bf16_t)(f[0] * sc); v[1] = (bf16_t)(f[1] * sc);
  v[2] = (bf16_t)(f[2] * sc); v[3] = (bf16_t)(f[3] * sc);
  return v;
}

// ---------------------------------------------------------------------------
// Prep: fp32 -> bf16: x (blocks 0..2047), packed W (2048..3583), Wo (3584..4095)
// ---------------------------------------------------------------------------
__global__ __launch_bounds__(256) void prep_kernel(
    const float* __restrict__ x,
    const float* __restrict__ q0, const float* __restrict__ q1,
    const float* __restrict__ k0, const float* __restrict__ k1,
    const float* __restrict__ v0, const float* __restrict__ v1,
    const float* __restrict__ wo,
    bf16_t* __restrict__ xb, bf16_t* __restrict__ Wb, bf16_t* __restrict__ Wob)
{
  const int bid = blockIdx.x;
  if (bid < 2048) {
    long i = ((long)bid * 256 + threadIdx.x) * 8;
    *(bf16x8*)&xb[i] = cvt8(*(const f32x4*)&x[i], *(const f32x4*)&x[i + 4]);
  } else if (bid < 3584) {
    int rb = bid - 2048;
    int sec = rb >> 5;                  // 0..47 = qkv*16 + h
    int qkv = sec >> 4, hh = sec & 15;
    const float* s = (qkv == 0) ? (hh < 8 ? q0 : q1)
                   : (qkv == 1) ? (hh < 8 ? k0 : k1)
                                : (hh < 8 ? v0 : v1);
    s += (long)(hh & 7) * (E_ * D_);
    long off = ((long)(rb & 31) * 256 + threadIdx.x) * 8;
    *(bf16x8*)&Wb[(long)sec * (E_ * D_) + off] =
        cvt8(*(const f32x4*)&s[off], *(const f32x4*)&s[off + 4]);
  } else {
    long i = ((long)(bid - 3584) * 256 + threadIdx.x) * 8;
    *(bf16x8*)&Wob[i] = cvt8(*(const f32x4*)&wo[i], *(const f32x4*)&wo[i + 4]);
  }
}

// ---------------------------------------------------------------------------
// Fused QKV GEMM, 128x128 tile, BK=64.  grid = (32, 24), 256 thr.
// Q/K: swapped-operand MFMA (C^T) -> swizzled-LDS round-trip -> coalesced
// b128 row-major stores.  V: normal orientation -> LDS transpose -> Vt.
// ---------------------------------------------------------------------------
__global__ __launch_bounds__(256) void qkv128_kernel(
    const bf16_t* __restrict__ xb, const bf16_t* __restrict__ Wb,
    bf16_t* __restrict__ Qb, bf16_t* __restrict__ Kb, bf16_t* __restrict__ Vt)
{
  __shared__ __align__(16) bf16_t smem[2 * 128 * 64];   // As | Bs; reused in epilogue
  bf16_t* As = smem;
  bf16_t* Bs = smem + 128 * 64;

  const int tid = threadIdx.x;
  const int wv = tid >> 6, lane = tid & 63, lane16 = lane & 15, half = lane >> 4;
  const int wm = wv >> 1, wn = wv & 1;
  const int mt = blockIdx.x, nt = blockIdx.y;
  const int sec = nt >> 3;              // 0=Q 1=K 2=V

  const bf16_t* Ag = xb + (long)mt * 128 * D_;
  const bf16_t* Bg = Wb + (long)nt * 128 * D_;

  f32x4 acc[4][4] = {};

  if (sec < 2) {
    for (int k0 = 0; k0 < D_; k0 += 64) {
      __syncthreads();
      stage128x64_async(Ag + k0, D_, As, tid);
      stage128x64_async(Bg + k0, D_, Bs, tid);
      __syncthreads();
#pragma unroll
      for (int ks = 0; ks < 2; ++ks) {
        bf16x8 a[4], b[4];
#pragma unroll
        for (int i = 0; i < 4; ++i) a[i] = frag_ld(As, wm * 64 + i * 16 + lane16, ks, half);
#pragma unroll
        for (int i = 0; i < 4; ++i) b[i] = frag_ld(Bs, wn * 64 + i * 16 + lane16, ks, half);
#pragma unroll
        for (int mi = 0; mi < 4; ++mi)
#pragma unroll
          for (int ni = 0; ni < 4; ++ni)
            acc[mi][ni] = __builtin_amdgcn_mfma_f32_16x16x32_bf16(b[ni], a[mi], acc[mi][ni], 0, 0, 0);
      }
    }
  } else {
    for (int k0 = 0; k0 < D_; k0 += 64) {
      __syncthreads();
      stage128x64_async(Ag + k0, D_, As, tid);
      stage128x64_async(Bg + k0, D_, Bs, tid);
      __syncthreads();
#pragma unroll
      for (int ks = 0; ks < 2; ++ks) {
        bf16x8 a[4], b[4];
#pragma unroll
        for (int i = 0; i < 4; ++i) a[i] = frag_ld(As, wm * 64 + i * 16 + lane16, ks, half);
#pragma unroll
        for (int i = 0; i < 4; ++i) b[i] = frag_ld(Bs, wn * 64 + i * 16 + lane16, ks, half);
#pragma unroll
        for (int mi = 0; mi < 4; ++mi)
#pragma unroll
          for (int ni = 0; ni < 4; ++ni)
            acc[mi][ni] = __builtin_amdgcn_mfma_f32_16x16x32_bf16(a[mi], b[ni], acc[mi][ni], 0, 0, 0);
      }
    }
  }

  const int tok0 = mt * 128;
  const int b  = tok0 >> 11;
  const int n0 = tok0 & 2047;

  if (sec < 2) {
    const float qs = (sec == 0) ? QSCALE : 1.0f;
    bf16_t* L = smem + wn * 8192;
    __syncthreads();
#pragma unroll
    for (int mi = 0; mi < 4; ++mi)
#pragma unroll
      for (int ni = 0; ni < 4; ++ni) {
        int tok = wm * 64 + 16 * mi + lane16;
        int cc  = (2 * ni + (half >> 1)) ^ (tok & 7);
        int sub = half & 1;
        *(bf16x4*)&L[tok * 64 + cc * 8 + sub * 4] = cvt4(acc[mi][ni], qs);
      }
    __syncthreads();
    bf16_t* dst = (sec == 0) ? Qb : Kb;
#pragma unroll
    for (int j = 0; j < 8; ++j) {
      int id = j * 256 + tid;             // 0..2047 = [c][tok][ec]
      int c = id >> 10, rem = id & 1023;
      int tok = rem >> 3, ec = rem & 7;
      int scc = ec ^ (tok & 7);
      bf16x8 v = *(const bf16x8*)&smem[c * 8192 + tok * 64 + scc * 8];
      int hh = (nt & 7) * 2 + c;
      *(bf16x8*)&dst[((long)(b * H_ + hh) * NTOK + n0 + tok) * E_ + ec * 8] = v;
    }
  } else {
#pragma unroll
    for (int c = 0; c < 2; ++c) {
      __syncthreads();
      if (wn == c) {
#pragma unroll
        for (int mi = 0; mi < 4; ++mi)
#pragma unroll
          for (int ni = 0; ni < 4; ++ni) {
            int t0v = wm * 64 + 16 * mi + half * 4;
            int e   = 16 * ni + lane16;
            *(bf16x4*)&smem[e * 144 + t0v] = cvt4(acc[mi][ni], 1.0f);
          }
      }
      __syncthreads();
      int hh = (nt & 7) * 2 + c;
      bf16_t* vdst = Vt + ((long)(b * H_ + hh) * E_) * NTOK;
#pragma unroll
      for (int q = 0; q < 4; ++q) {
        int chunk = q * 256 + tid;
        int e = chunk >> 4, toff = (chunk & 15) * 8;
        *(bf16x8*)&vdst[(long)e * NTOK + n0 + toff] = *(const bf16x8*)&smem[e * 144 + toff];
      }
    }
  }
}

// ---------------------------------------------------------------------------
// Flash attention v3c: one q-tile per block, waves split KEY groups.
// grid = (32 qb-swizzled, 16 heads, 2 batch) = 1024 blocks, 256 thr.
// LDS cut to 32 KB by UNIONING the epilogue reduction buffers (Or/Lr) with
// the dead K/V staging buffers -> 5 blocks/CU co-resident (was 3).  All 4
// assigned blocks per CU now overlap instead of running ~serially.
// ---------------------------------------------------------------------------
__global__ __launch_bounds__(256, 5) void attn_kernel(
    const bf16_t* __restrict__ Qb, const bf16_t* __restrict__ Kb,
    const bf16_t* __restrict__ Vt, bf16_t* __restrict__ Ob)
{
  __shared__ __align__(16) char smem_raw[32768];   // Kl[2]|Vl[2]  ∪  Or|Lr
  bf16_t* Kl0 = (bf16_t*)smem_raw;                 // [2][64*64]
  bf16_t* Vl0 = Kl0 + 2 * 64 * 64;                 // [2][64*64]
  float*  Or  = (float*)smem_raw;                  // [64*68] (epilogue only)
  float*  Lr  = Or + 64 * 68;                      // [4][64] (epilogue only)

  const int tid = threadIdx.x;
  const int wv = tid >> 6, lane = tid & 63, lane16 = lane & 15, half = lane >> 4;
  const int xb_ = blockIdx.x;
  const int qb = (xb_ & 1) ? (31 - (xb_ >> 1)) : (xb_ >> 1);  // short/long interleave
  const int h = blockIdx.y, b = blockIdx.z;
  const bool causal = (h < 8);
  const long bh = (long)(b * H_ + h);

  // Q tile -> registers (B-operand layout): qf[qblk][ks]
  bf16x8 qf[4][2];
  {
    const bf16_t* qg = Qb + (bh * NTOK + (long)qb * 64) * E_;
#pragma unroll
    for (int qblk = 0; qblk < 4; ++qblk) {
      const bf16_t* r = qg + (16 * qblk + lane16) * E_;
      qf[qblk][0] = *(const bf16x8*)(r + half * 8);
      qf[qblk][1] = *(const bf16x8*)(r + 32 + half * 8);
    }
  }

  f32x4 oacc[4][4] = {};     // [eblk][qblk]: row e=4half+r, col q=lane16 (partial: own keys)
  float l_acc[4] = {};       // per qblk, this lane's q, own keys

  const int lo = causal ? 0 : qb;
  const int hi = causal ? qb : 31;

  stage64_async(Kb + (bh * NTOK + (long)lo * 64) * E_, E_, Kl0, tid);
  stage64_async(Vt + bh * E_ * NTOK + (long)lo * 64, NTOK, Vl0, tid);

  for (int kb = lo; kb <= hi; ++kb) {
    const int cur = (kb - lo) & 1;
    bf16_t* Klc = Kl0 + cur * 4096;
    bf16_t* Vlc = Vl0 + cur * 4096;
    __syncthreads();   // staging of cur visible; prev iter's reads of cur^1 done
    if (kb < hi) {
      stage64_async(Kb + (bh * NTOK + (long)(kb + 1) * 64) * E_, E_, Kl0 + (cur ^ 1) * 4096, tid);
      stage64_async(Vt + bh * E_ * NTOK + (long)(kb + 1) * 64, NTOK, Vl0 + (cur ^ 1) * 4096, tid);
    }

    // this wave's K fragment (16 own keys x 64 e)
    bf16x8 kf0 = frag_ld(Klc, 16 * wv + lane16, 0, half);
    bf16x8 kf1 = frag_ld(Klc, 16 * wv + lane16, 1, half);

    // S^T: col=q(lane16), rows = own keys 4half..4half+3
    f32x4 s[4] = {};
#pragma unroll
    for (int qblk = 0; qblk < 4; ++qblk) {
      s[qblk] = __builtin_amdgcn_mfma_f32_16x16x32_bf16(kf0, qf[qblk][0], s[qblk], 0, 0, 0);
      s[qblk] = __builtin_amdgcn_mfma_f32_16x16x32_bf16(kf1, qf[qblk][1], s[qblk], 0, 0, 0);
    }

    if (kb == qb) {    // diagonal block: token-level mask
#pragma unroll
      for (int qblk = 0; qblk < 4; ++qblk)
#pragma unroll
        for (int r = 0; r < 4; ++r) {
          int key = 16 * wv + 4 * half + r;
          int q   = 16 * qblk + lane16;
          bool ok = causal ? (q >= key) : (q <= key);
          s[qblk][r] = ok ? s[qblk][r] : NEG_BIG;
        }
    }

    // p = exp2(s), per-lane l partials, pack P in registers (B-op of mfma16)
    bf16x4 pb[4];
#pragma unroll
    for (int qblk = 0; qblk < 4; ++qblk) {
      float ls = 0.f;
#pragma unroll
      for (int r = 0; r < 4; ++r) {
        float p = exp2f(s[qblk][r]);
        s[qblk][r] = p;
        ls += p;
      }
      l_acc[qblk] += ls;
      pb[qblk] = cvt4(s[qblk], 1.0f);
    }

    // V fragments (A-op of mfma16): Vl[e=16eblk+lane16][own keys 16wv+4half..+3]
    bf16x4 vf[4];
#pragma unroll
    for (int eblk = 0; eblk < 4; ++eblk) {
      int row = 16 * eblk + lane16;
      int cc  = (2 * wv + (half >> 1)) ^ (row & 7);
      vf[eblk] = *(const bf16x4*)&Vlc[row * 64 + cc * 8 + (half & 1) * 4];
    }

    // O^T partial += V * P  (K=16: own keys only)
#pragma unroll
    for (int eblk = 0; eblk < 4; ++eblk)
#pragma unroll
      for (int qblk = 0; qblk < 4; ++qblk)
        oacc[eblk][qblk] = mfma16(vf[eblk], pb[qblk], oacc[eblk][qblk]);
  }

  // l: reduce over half-groups (register-only shuffles)
#pragma unroll
  for (int qblk = 0; qblk < 4; ++qblk) {
    l_acc[qblk] += __shfl_xor(l_acc[qblk], 16, 64);
    l_acc[qblk] += __shfl_xor(l_acc[qblk], 32, 64);
  }

  __syncthreads();   // all waves done reading Kl/Vl -> safe to overlay Or/Lr

  if (half == 0) {
#pragma unroll
    for (int qblk = 0; qblk < 4; ++qblk)
      Lr[wv * 64 + 16 * qblk + lane16] = l_acc[qblk];
  }

  // O cross-wave reduction: rotating q-quarter rounds; quarter index qq is
  // wave-uniform -> static register indexing (no scratch spill).
#pragma unroll
  for (int r = 0; r < 4; ++r) {
    const int qq = (wv + r) & 3;          // wave-uniform
    f32x4 part[4];
    if (qq == 0) {
      part[0] = oacc[0][0]; part[1] = oacc[1][0]; part[2] = oacc[2][0]; part[3] = oacc[3][0];
    } else if (qq == 1) {
      part[0] = oacc[0][1]; part[1] = oacc[1][1]; part[2] = oacc[2][1]; part[3] = oacc[3][1];
    } else if (qq == 2) {
      part[0] = oacc[0][2]; part[1] = oacc[1][2]; part[2] = oacc[2][2]; part[3] = oacc[3][2];
    } else {
      part[0] = oacc[0][3]; part[1] = oacc[1][3]; part[2] = oacc[2][3]; part[3] = oacc[3][3];
    }
#pragma unroll
    for (int eblk = 0; eblk < 4; ++eblk) {
      float* p = &Or[(16 * qq + lane16) * 68 + 16 * eblk + 4 * half];
      if (r == 0) {
        *(f32x4*)p = part[eblk];
      } else {
        f32x4 v = *(const f32x4*)p;
        v += part[eblk];
        *(f32x4*)p = v;
      }
    }
    __syncthreads();
  }

  // normalize + store: thread -> (q = tid>>2, 16 e's)
  {
    int q = tid >> 2, e0 = (tid & 3) * 16;
    float l = Lr[0 * 64 + q] + Lr[1 * 64 + q] + Lr[2 * 64 + q] + Lr[3 * 64 + q];
    float rcp = 1.0f / l;
    const float* src = &Or[q * 68 + e0];
    f32x4 v0 = *(const f32x4*)(src + 0)  * rcp;
    f32x4 v1 = *(const f32x4*)(src + 4)  * rcp;
    f32x4 v2 = *(const f32x4*)(src + 8)  * rcp;
    f32x4 v3 = *(const f32x4*)(src + 12) * rcp;
    bf16_t* og = Ob + (bh * NTOK + (long)qb * 64 + q) * E_ + e0;
    *(bf16x8*)(og)     = cvt8(v0, v1);
    *(bf16x8*)(og + 8) = cvt8(v2, v3);
  }
}

// ---------------------------------------------------------------------------
// Output projection, 128x128 tile, swapped-operand MFMA + swizzled-LDS
// epilogue -> coalesced f32x4 stores.  grid = (32, 8), 256 thr.
// ---------------------------------------------------------------------------
__global__ __launch_bounds__(256) void oproj128_kernel(
    const bf16_t* __restrict__ Ob, const bf16_t* __restrict__ Wob,
    float* __restrict__ res)
{
  __shared__ __align__(16) bf16_t smem[2 * 128 * 64];
  bf16_t* As = smem;
  bf16_t* Bs = smem + 128 * 64;

  const int tid = threadIdx.x;
  const int wv = tid >> 6, lane = tid & 63, lane16 = lane & 15, half = lane >> 4;
  const int wm = wv >> 1, wn = wv & 1;
  const int mt = blockIdx.x, nt = blockIdx.y;

  const bf16_t* Ag = Ob  + (long)mt * 128 * D_;
  const bf16_t* Bg = Wob + (long)nt * 128 * D_;

  f32x4 acc[4][4] = {};

  for (int k0 = 0; k0 < D_; k0 += 64) {
    __syncthreads();
    stage128x64_async(Ag + k0, D_, As, tid);
    stage128x64_async(Bg + k0, D_, Bs, tid);
    __syncthreads();
#pragma unroll
    for (int ks = 0; ks < 2; ++ks) {
      bf16x8 a[4], b[4];
#pragma unroll
      for (int i = 0; i < 4; ++i) a[i] = frag_ld(As, wm * 64 + i * 16 + lane16, ks, half);
#pragma unroll
      for (int i = 0; i < 4; ++i) b[i] = frag_ld(Bs, wn * 64 + i * 16 + lane16, ks, half);
#pragma unroll
      for (int mi = 0; mi < 4; ++mi)
#pragma unroll
        for (int ni = 0; ni < 4; ++ni)
          acc[mi][ni] = __builtin_amdgcn_mfma_f32_16x16x32_bf16(b[ni], a[mi], acc[mi][ni], 0, 0, 0);
    }
  }

  float* Lf = (float*)smem;              // [128 tok][64 col] f32, 16B-chunk XOR tok&15
#pragma unroll
  for (int pass = 0; pass < 2; ++pass) {
    __syncthreads();
    if (wn == pass) {
#pragma unroll
      for (int mi = 0; mi < 4; ++mi)
#pragma unroll
        for (int ni = 0; ni < 4; ++ni) {
          int tok = wm * 64 + 16 * mi + lane16;
          int cc  = (4 * ni + half) ^ (tok & 15);
          *(f32x4*)&Lf[tok * 64 + cc * 4] = acc[mi][ni];
        }
    }
    __syncthreads();
#pragma unroll
    for (int j = 0; j < 8; ++j) {
      int id = j * 256 + tid;             // 0..2047 = [tok][c]
      int tok = id >> 4, c = id & 15;
      int cc = c ^ (tok & 15);
      f32x4 v = *(const f32x4*)&Lf[tok * 64 + cc * 4];
      *(f32x4*)&res[(long)(mt * 128 + tok) * D_ + nt * 128 + pass * 64 + c * 4] = v;
    }
  }
}

// ---------------------------------------------------------------------------
// Copy fp32 result scratch -> d_out (16 MB)  [fallback path only]
// ---------------------------------------------------------------------------
__global__ __launch_bounds__(256) void copy_kernel(const float* __restrict__ src,
                                                   float* __restrict__ dst) {
  long i = ((long)blockIdx.x * 256 + threadIdx.x) * 8;
  *(f32x4*)&dst[i]     = *(const f32x4*)&src[i];
  *(f32x4*)&dst[i + 4] = *(const f32x4*)&src[i + 4];
}

// ---------------------------------------------------------------------------
extern "C" void kernel_launch(void* const* d_in, const int* in_sizes, int n_in,
                              void* d_out, int out_size, void* d_ws, size_t ws_size,
                              hipStream_t stream) {
  const float* x     = (const float*)d_in[0];
  const float* wq_lb = (const float*)d_in[1];
  const float* wk_lb = (const float*)d_in[2];
  const float* wv_lb = (const float*)d_in[3];
  const float* wq_la = (const float*)d_in[4];
  const float* wk_la = (const float*)d_in[5];
  const float* wv_la = (const float*)d_in[6];
  const float* wo    = (const float*)d_in[7];
  float* out = (float*)d_out;

  const size_t per_buf = (size_t)B_ * H_ * NTOK * E_;   // 4M elems (8MB bf16)

  bf16_t* Qb = (bf16_t*)d_ws;
  bf16_t* Kb = Qb + per_buf;
  bf16_t* Vt = Kb + per_buf;

  bf16_t* xb = (bf16_t*)d_out;
  bf16_t* Wb = xb + per_buf;

  const bool direct = ws_size >= (size_t)34 * 1024 * 1024;

  if (direct) {
    bf16_t* Ob  = Vt + per_buf;
    bf16_t* Wob = Ob + per_buf;
    prep_kernel<<<4096, 256, 0, stream>>>(x, wq_lb, wq_la, wk_lb, wk_la,
                                          wv_lb, wv_la, wo, xb, Wb, Wob);
    qkv128_kernel<<<dim3(32, 24), 256, 0, stream>>>(xb, Wb, Qb, Kb, Vt);
    attn_kernel<<<dim3(32, 16, 2), 256, 0, stream>>>(Qb, Kb, Vt, Ob);
    oproj128_kernel<<<dim3(32, 8), 256, 0, stream>>>(Ob, Wob, out);
  } else {
    bf16_t* Wob = Wb + (size_t)3 * 1024 * 1024;
    bf16_t* Ob  = (bf16_t*)d_out;
    float*  res = (float*)d_ws;
    prep_kernel<<<4096, 256, 0, stream>>>(x, wq_lb, wq_la, wk_lb, wk_la,
                                          wv_lb, wv_la, wo, xb, Wb, Wob);
    qkv128_kernel<<<dim3(32, 24), 256, 0, stream>>>(xb, Wb, Qb, Kb, Vt);
    attn_kernel<<<dim3(32, 16, 2), 256, 0, stream>>>(Qb, Kb, Vt, Ob);
    oproj128_kernel<<<dim3(32, 8), 256, 0, stream>>>(Ob, Wob, res);
    copy_kernel<<<2048, 256, 0, stream>>>(res, out);
  }
}

// Round 12
// 196.410 us; speedup vs baseline: 1.7572x; 1.7572x over previous
//
#include <hip/hip_runtime.h>
#include <hip/hip_bf16.h>

// Problem constants
constexpr int B_    = 2;
constexpr int NTOK  = 2048;   // T*F per batch
constexpr int D_    = 1024;
constexpr int H_    = 16;
constexpr int E_    = 64;     // head dim

using bf16_t = __bf16;
using bf16x8 = __attribute__((ext_vector_type(8))) __bf16;
using bf16x4 = __attribute__((ext_vector_type(4))) __bf16;
using f32x4  = __attribute__((ext_vector_type(4))) float;
using s16x4  = __attribute__((ext_vector_type(4))) short;

#define NEG_BIG  (-30000.0f)          // finite mask sentinel (exp2 -> 0, never NaN)
#define QSCALE   (0.125f * 1.44269504088896f)   // 1/sqrt(64) * log2(e): exp2-domain softmax

// K=16 bf16 MFMA (carried-forward shape; two builtin naming conventions)
#if __has_builtin(__builtin_amdgcn_mfma_f32_16x16x16_bf16)
__device__ __forceinline__ f32x4 mfma16(bf16x4 a, bf16x4 b, f32x4 c) {
  return __builtin_amdgcn_mfma_f32_16x16x16_bf16(a, b, c, 0, 0, 0);
}
#else
__device__ __forceinline__ f32x4 mfma16(bf16x4 a, bf16x4 b, f32x4 c) {
  return __builtin_amdgcn_mfma_f32_16x16x16bf16_1k(
      __builtin_bit_cast(s16x4, a), __builtin_bit_cast(s16x4, b), c, 0, 0, 0);
}
#endif

// ---- async global->LDS 16B. LDS dest = wave-uniform base + lane*16.
__device__ __forceinline__ void load16_to_lds(const void* g, void* l) {
  __builtin_amdgcn_global_load_lds((const __attribute__((address_space(1))) void*)g,
                                   (__attribute__((address_space(3))) void*)l, 16, 0, 0);
}

// Stage 64x64 bf16 tile into LDS [64][64] with per-row XOR column-chunk swizzle.
__device__ __forceinline__ void stage64_async(const bf16_t* __restrict__ g, int gs,
                                              bf16_t* l, int tid) {
#pragma unroll
  for (int j = 0; j < 2; ++j) {
    int chunk = j * 256 + tid;            // 0..511, 16B each
    int row = chunk >> 3, cc = chunk & 7;
    int gcc = cc ^ (row & 7);
    load16_to_lds(g + (long)row * gs + gcc * 8, l + chunk * 8);
  }
}

// Stage 128x64 bf16 tile, same swizzle
__device__ __forceinline__ void stage128x64_async(const bf16_t* __restrict__ g, int gs,
                                                  bf16_t* l, int tid) {
#pragma unroll
  for (int j = 0; j < 4; ++j) {
    int chunk = j * 256 + tid;            // 0..1023
    int row = chunk >> 3, cc = chunk & 7;
    int gcc = cc ^ (row & 7);
    load16_to_lds(g + (long)row * gs + gcc * 8, l + chunk * 8);
  }
}

// Read an 8-elem MFMA fragment (global colchunk = ks*4+half) from swizzled LDS tile
__device__ __forceinline__ bf16x8 frag_ld(const bf16_t* l, int row, int ks, int half) {
  int cc = (ks * 4 + half) ^ (row & 7);
  return *(const bf16x8*)&l[row * 64 + cc * 8];
}

__device__ __forceinline__ bf16x8 cvt8(f32x4 f0, f32x4 f1) {
  bf16x8 v;
  v[0] = (bf16_t)f0[0]; v[1] = (bf16_t)f0[1]; v[2] = (bf16_t)f0[2]; v[3] = (bf16_t)f0[3];
  v[4] = (bf16_t)f1[0]; v[5] = (bf16_t)f1[1]; v[6] = (bf16_t)f1[2]; v[7] = (bf16_t)f1[3];
  return v;
}

__device__ __forceinline__ bf16x4 cvt4(f32x4 f, float sc) {
  bf16x4 v;
  v[0] = (bf16_t)(f[0] * sc); v[1] = (bf16_t)(f[1] * sc);
  v[2] = (bf16_t)(f[2] * sc); v[3] = (bf16_t)(f[3] * sc);
  return v;
}

// ---------------------------------------------------------------------------
// Prep: fp32 -> bf16: x (blocks 0..2047), packed W (2048..3583), Wo (3584..4095)
// ---------------------------------------------------------------------------
__global__ __launch_bounds__(256) void prep_kernel(
    const float* __restrict__ x,
    const float* __restrict__ q0, const float* __restrict__ q1,
    const float* __restrict__ k0, const float* __restrict__ k1,
    const float* __restrict__ v0, const float* __restrict__ v1,
    const float* __restrict__ wo,
    bf16_t* __restrict__ xb, bf16_t* __restrict__ Wb, bf16_t* __restrict__ Wob)
{
  const int bid = blockIdx.x;
  if (bid < 2048) {
    long i = ((long)bid * 256 + threadIdx.x) * 8;
    *(bf16x8*)&xb[i] = cvt8(*(const f32x4*)&x[i], *(const f32x4*)&x[i + 4]);
  } else if (bid < 3584) {
    int rb = bid - 2048;
    int sec = rb >> 5;                  // 0..47 = qkv*16 + h
    int qkv = sec >> 4, hh = sec & 15;
    const float* s = (qkv == 0) ? (hh < 8 ? q0 : q1)
                   : (qkv == 1) ? (hh < 8 ? k0 : k1)
                                : (hh < 8 ? v0 : v1);
    s += (long)(hh & 7) * (E_ * D_);
    long off = ((long)(rb & 31) * 256 + threadIdx.x) * 8;
    *(bf16x8*)&Wb[(long)sec * (E_ * D_) + off] =
        cvt8(*(const f32x4*)&s[off], *(const f32x4*)&s[off + 4]);
  } else {
    long i = ((long)(bid - 3584) * 256 + threadIdx.x) * 8;
    *(bf16x8*)&Wob[i] = cvt8(*(const f32x4*)&wo[i], *(const f32x4*)&wo[i + 4]);
  }
}

// ---------------------------------------------------------------------------
// Fused QKV GEMM, 128x128 tile, BK=64.  grid = (32, 24), 256 thr.
// Q/K: swapped-operand MFMA (C^T) -> swizzled-LDS round-trip -> coalesced
// b128 row-major stores.  V: normal orientation -> LDS transpose -> Vt.
// ---------------------------------------------------------------------------
__global__ __launch_bounds__(256) void qkv128_kernel(
    const bf16_t* __restrict__ xb, const bf16_t* __restrict__ Wb,
    bf16_t* __restrict__ Qb, bf16_t* __restrict__ Kb, bf16_t* __restrict__ Vt)
{
  __shared__ __align__(16) bf16_t smem[2 * 128 * 64];   // As | Bs; reused in epilogue
  bf16_t* As = smem;
  bf16_t* Bs = smem + 128 * 64;

  const int tid = threadIdx.x;
  const int wv = tid >> 6, lane = tid & 63, lane16 = lane & 15, half = lane >> 4;
  const int wm = wv >> 1, wn = wv & 1;
  const int mt = blockIdx.x, nt = blockIdx.y;
  const int sec = nt >> 3;              // 0=Q 1=K 2=V

  const bf16_t* Ag = xb + (long)mt * 128 * D_;
  const bf16_t* Bg = Wb + (long)nt * 128 * D_;

  f32x4 acc[4][4] = {};

  if (sec < 2) {
    for (int k0 = 0; k0 < D_; k0 += 64) {
      __syncthreads();
      stage128x64_async(Ag + k0, D_, As, tid);
      stage128x64_async(Bg + k0, D_, Bs, tid);
      __syncthreads();
#pragma unroll
      for (int ks = 0; ks < 2; ++ks) {
        bf16x8 a[4], b[4];
#pragma unroll
        for (int i = 0; i < 4; ++i) a[i] = frag_ld(As, wm * 64 + i * 16 + lane16, ks, half);
#pragma unroll
        for (int i = 0; i < 4; ++i) b[i] = frag_ld(Bs, wn * 64 + i * 16 + lane16, ks, half);
#pragma unroll
        for (int mi = 0; mi < 4; ++mi)
#pragma unroll
          for (int ni = 0; ni < 4; ++ni)
            acc[mi][ni] = __builtin_amdgcn_mfma_f32_16x16x32_bf16(b[ni], a[mi], acc[mi][ni], 0, 0, 0);
      }
    }
  } else {
    for (int k0 = 0; k0 < D_; k0 += 64) {
      __syncthreads();
      stage128x64_async(Ag + k0, D_, As, tid);
      stage128x64_async(Bg + k0, D_, Bs, tid);
      __syncthreads();
#pragma unroll
      for (int ks = 0; ks < 2; ++ks) {
        bf16x8 a[4], b[4];
#pragma unroll
        for (int i = 0; i < 4; ++i) a[i] = frag_ld(As, wm * 64 + i * 16 + lane16, ks, half);
#pragma unroll
        for (int i = 0; i < 4; ++i) b[i] = frag_ld(Bs, wn * 64 + i * 16 + lane16, ks, half);
#pragma unroll
        for (int mi = 0; mi < 4; ++mi)
#pragma unroll
          for (int ni = 0; ni < 4; ++ni)
            acc[mi][ni] = __builtin_amdgcn_mfma_f32_16x16x32_bf16(a[mi], b[ni], acc[mi][ni], 0, 0, 0);
      }
    }
  }

  const int tok0 = mt * 128;
  const int b  = tok0 >> 11;
  const int n0 = tok0 & 2047;

  if (sec < 2) {
    const float qs = (sec == 0) ? QSCALE : 1.0f;
    bf16_t* L = smem + wn * 8192;
    __syncthreads();
#pragma unroll
    for (int mi = 0; mi < 4; ++mi)
#pragma unroll
      for (int ni = 0; ni < 4; ++ni) {
        int tok = wm * 64 + 16 * mi + lane16;
        int cc  = (2 * ni + (half >> 1)) ^ (tok & 7);
        int sub = half & 1;
        *(bf16x4*)&L[tok * 64 + cc * 8 + sub * 4] = cvt4(acc[mi][ni], qs);
      }
    __syncthreads();
    bf16_t* dst = (sec == 0) ? Qb : Kb;
#pragma unroll
    for (int j = 0; j < 8; ++j) {
      int id = j * 256 + tid;             // 0..2047 = [c][tok][ec]
      int c = id >> 10, rem = id & 1023;
      int tok = rem >> 3, ec = rem & 7;
      int scc = ec ^ (tok & 7);
      bf16x8 v = *(const bf16x8*)&smem[c * 8192 + tok * 64 + scc * 8];
      int hh = (nt & 7) * 2 + c;
      *(bf16x8*)&dst[((long)(b * H_ + hh) * NTOK + n0 + tok) * E_ + ec * 8] = v;
    }
  } else {
#pragma unroll
    for (int c = 0; c < 2; ++c) {
      __syncthreads();
      if (wn == c) {
#pragma unroll
        for (int mi = 0; mi < 4; ++mi)
#pragma unroll
          for (int ni = 0; ni < 4; ++ni) {
            int t0v = wm * 64 + 16 * mi + half * 4;
            int e   = 16 * ni + lane16;
            *(bf16x4*)&smem[e * 144 + t0v] = cvt4(acc[mi][ni], 1.0f);
          }
      }
      __syncthreads();
      int hh = (nt & 7) * 2 + c;
      bf16_t* vdst = Vt + ((long)(b * H_ + hh) * E_) * NTOK;
#pragma unroll
      for (int q = 0; q < 4; ++q) {
        int chunk = q * 256 + tid;
        int e = chunk >> 4, toff = (chunk & 15) * 8;
        *(bf16x8*)&vdst[(long)e * NTOK + n0 + toff] = *(const bf16x8*)&smem[e * 144 + toff];
      }
    }
  }
}

// ---------------------------------------------------------------------------
// Flash attention (EXACT R9 kernel — proven pass @57.7us): one q-tile per
// block, waves split KEY groups.  grid = (32, 16, 2), 256 thr.  Separate
// __shared__ buffers (51.2 KB) — the Or/Lr-over-K/V union (R10/R11) is
// quarantined: R11 failed correctness with it at healthy register counts.
// ---------------------------------------------------------------------------
__global__ __launch_bounds__(256, 3) void attn_kernel(
    const bf16_t* __restrict__ Qb, const bf16_t* __restrict__ Kb,
    const bf16_t* __restrict__ Vt, bf16_t* __restrict__ Ob)
{
  __shared__ __align__(16) bf16_t Kl[2][64 * 64];
  __shared__ __align__(16) bf16_t Vl[2][64 * 64];
  __shared__ __align__(16) float  Or[64 * 68];   // [q][e] pad-68 reduction buffer
  __shared__ float Lr[4][64];                    // per-wave l partial per q

  const int tid = threadIdx.x;
  const int wv = tid >> 6, lane = tid & 63, lane16 = lane & 15, half = lane >> 4;
  const int xb_ = blockIdx.x;
  const int qb = (xb_ & 1) ? (31 - (xb_ >> 1)) : (xb_ >> 1);  // short/long interleave
  const int h = blockIdx.y, b = blockIdx.z;
  const bool causal = (h < 8);
  const long bh = (long)(b * H_ + h);

  // Q tile -> registers (B-operand layout): qf[qblk][ks]
  bf16x8 qf[4][2];
  {
    const bf16_t* qg = Qb + (bh * NTOK + (long)qb * 64) * E_;
#pragma unroll
    for (int qblk = 0; qblk < 4; ++qblk) {
      const bf16_t* r = qg + (16 * qblk + lane16) * E_;
      qf[qblk][0] = *(const bf16x8*)(r + half * 8);
      qf[qblk][1] = *(const bf16x8*)(r + 32 + half * 8);
    }
  }

  f32x4 oacc[4][4] = {};     // [eblk][qblk]: row e=4half+r, col q=lane16 (partial: own keys)
  float l_acc[4] = {};       // per qblk, this lane's q, own keys

  const int lo = causal ? 0 : qb;
  const int hi = causal ? qb : 31;

  stage64_async(Kb + (bh * NTOK + (long)lo * 64) * E_, E_, Kl[0], tid);
  stage64_async(Vt + bh * E_ * NTOK + (long)lo * 64, NTOK, Vl[0], tid);

  for (int kb = lo; kb <= hi; ++kb) {
    const int cur = (kb - lo) & 1;
    __syncthreads();   // staging of cur visible; prev iter's reads of cur^1 done
    if (kb < hi) {
      stage64_async(Kb + (bh * NTOK + (long)(kb + 1) * 64) * E_, E_, Kl[cur ^ 1], tid);
      stage64_async(Vt + bh * E_ * NTOK + (long)(kb + 1) * 64, NTOK, Vl[cur ^ 1], tid);
    }

    // this wave's K fragment (16 own keys x 64 e)
    bf16x8 kf0 = frag_ld(Kl[cur], 16 * wv + lane16, 0, half);
    bf16x8 kf1 = frag_ld(Kl[cur], 16 * wv + lane16, 1, half);

    // S^T: col=q(lane16), rows = own keys 4half..4half+3
    f32x4 s[4] = {};
#pragma unroll
    for (int qblk = 0; qblk < 4; ++qblk) {
      s[qblk] = __builtin_amdgcn_mfma_f32_16x16x32_bf16(kf0, qf[qblk][0], s[qblk], 0, 0, 0);
      s[qblk] = __builtin_amdgcn_mfma_f32_16x16x32_bf16(kf1, qf[qblk][1], s[qblk], 0, 0, 0);
    }

    if (kb == qb) {    // diagonal block: token-level mask
#pragma unroll
      for (int qblk = 0; qblk < 4; ++qblk)
#pragma unroll
        for (int r = 0; r < 4; ++r) {
          int key = 16 * wv + 4 * half + r;
          int q   = 16 * qblk + lane16;
          bool ok = causal ? (q >= key) : (q <= key);
          s[qblk][r] = ok ? s[qblk][r] : NEG_BIG;
        }
    }

    // p = exp2(s), per-lane l partials, pack P in registers (B-op of mfma16)
    bf16x4 pb[4];
#pragma unroll
    for (int qblk = 0; qblk < 4; ++qblk) {
      float ls = 0.f;
#pragma unroll
      for (int r = 0; r < 4; ++r) {
        float p = exp2f(s[qblk][r]);
        s[qblk][r] = p;
        ls += p;
      }
      l_acc[qblk] += ls;
      pb[qblk] = cvt4(s[qblk], 1.0f);
    }

    // V fragments (A-op of mfma16): Vl[e=16eblk+lane16][own keys 16wv+4half..+3]
    bf16x4 vf[4];
#pragma unroll
    for (int eblk = 0; eblk < 4; ++eblk) {
      int row = 16 * eblk + lane16;
      int cc  = (2 * wv + (half >> 1)) ^ (row & 7);
      vf[eblk] = *(const bf16x4*)&Vl[cur][row * 64 + cc * 8 + (half & 1) * 4];
    }

    // O^T partial += V * P  (K=16: own keys only)
#pragma unroll
    for (int eblk = 0; eblk < 4; ++eblk)
#pragma unroll
      for (int qblk = 0; qblk < 4; ++qblk)
        oacc[eblk][qblk] = mfma16(vf[eblk], pb[qblk], oacc[eblk][qblk]);
  }

  // l: reduce over half-groups (4-key subsets) -> per-(wave,q); publish to LDS
#pragma unroll
  for (int qblk = 0; qblk < 4; ++qblk) {
    l_acc[qblk] += __shfl_xor(l_acc[qblk], 16, 64);
    l_acc[qblk] += __shfl_xor(l_acc[qblk], 32, 64);
  }
  if (half == 0) {
#pragma unroll
    for (int qblk = 0; qblk < 4; ++qblk)
      Lr[wv][16 * qblk + lane16] = l_acc[qblk];
  }

  // O cross-wave reduction: rotating q-quarter rounds; quarter index qq is
  // wave-uniform -> static register indexing (no scratch spill).
#pragma unroll
  for (int r = 0; r < 4; ++r) {
    const int qq = (wv + r) & 3;          // wave-uniform
    f32x4 part[4];
    if (qq == 0) {
      part[0] = oacc[0][0]; part[1] = oacc[1][0]; part[2] = oacc[2][0]; part[3] = oacc[3][0];
    } else if (qq == 1) {
      part[0] = oacc[0][1]; part[1] = oacc[1][1]; part[2] = oacc[2][1]; part[3] = oacc[3][1];
    } else if (qq == 2) {
      part[0] = oacc[0][2]; part[1] = oacc[1][2]; part[2] = oacc[2][2]; part[3] = oacc[3][2];
    } else {
      part[0] = oacc[0][3]; part[1] = oacc[1][3]; part[2] = oacc[2][3]; part[3] = oacc[3][3];
    }
#pragma unroll
    for (int eblk = 0; eblk < 4; ++eblk) {
      float* p = &Or[(16 * qq + lane16) * 68 + 16 * eblk + 4 * half];
      if (r == 0) {
        *(f32x4*)p = part[eblk];
      } else {
        f32x4 v = *(const f32x4*)p;
        v += part[eblk];
        *(f32x4*)p = v;
      }
    }
    __syncthreads();
  }

  // normalize + store: thread -> (q = tid>>2, 16 e's)
  {
    int q = tid >> 2, e0 = (tid & 3) * 16;
    float l = Lr[0][q] + Lr[1][q] + Lr[2][q] + Lr[3][q];
    float rcp = 1.0f / l;
    const float* src = &Or[q * 68 + e0];
    f32x4 v0 = *(const f32x4*)(src + 0)  * rcp;
    f32x4 v1 = *(const f32x4*)(src + 4)  * rcp;
    f32x4 v2 = *(const f32x4*)(src + 8)  * rcp;
    f32x4 v3 = *(const f32x4*)(src + 12) * rcp;
    bf16_t* og = Ob + (bh * NTOK + (long)qb * 64 + q) * E_ + e0;
    *(bf16x8*)(og)     = cvt8(v0, v1);
    *(bf16x8*)(og + 8) = cvt8(v2, v3);
  }
}

// ---------------------------------------------------------------------------
// Output projection, 64x128 tile (was 128x128: only 256 blocks = 1 block/CU,
// staging latency fully exposed).  grid = (64, 8) = 512 blocks -> 2/CU.
// Swapped-operand MFMA + swizzled-LDS epilogue -> coalesced f32x4 stores.
// ---------------------------------------------------------------------------
__global__ __launch_bounds__(256) void oproj64_kernel(
    const bf16_t* __restrict__ Ob, const bf16_t* __restrict__ Wob,
    float* __restrict__ res)
{
  __shared__ __align__(16) bf16_t smem[(64 + 128) * 64];   // As(64x64) | Bs(128x64)
  bf16_t* As = smem;
  bf16_t* Bs = smem + 64 * 64;

  const int tid = threadIdx.x;
  const int wv = tid >> 6, lane = tid & 63, lane16 = lane & 15, half = lane >> 4;
  const int wm = wv >> 1, wn = wv & 1;
  const int mt = blockIdx.x, nt = blockIdx.y;

  const bf16_t* Ag = Ob  + (long)mt * 64 * D_;
  const bf16_t* Bg = Wob + (long)nt * 128 * D_;

  f32x4 acc[2][4] = {};   // C^T micro-tiles: [mi tok-block][ni outcol-block]

  for (int k0 = 0; k0 < D_; k0 += 64) {
    __syncthreads();
    stage64_async(Ag + k0, D_, As, tid);
    stage128x64_async(Bg + k0, D_, Bs, tid);
    __syncthreads();
#pragma unroll
    for (int ks = 0; ks < 2; ++ks) {
      bf16x8 a[2], b[4];
#pragma unroll
      for (int i = 0; i < 2; ++i) a[i] = frag_ld(As, wm * 32 + i * 16 + lane16, ks, half);
#pragma unroll
      for (int i = 0; i < 4; ++i) b[i] = frag_ld(Bs, wn * 64 + i * 16 + lane16, ks, half);
#pragma unroll
      for (int mi = 0; mi < 2; ++mi)
#pragma unroll
        for (int ni = 0; ni < 4; ++ni)
          acc[mi][ni] = __builtin_amdgcn_mfma_f32_16x16x32_bf16(b[ni], a[mi], acc[mi][ni], 0, 0, 0);
    }
  }

  // epilogue: two passes (one per wn-half) through 16KB fp32 swizzled LDS
  float* Lf = (float*)smem;              // [64 tok][64 col] f32, 16B-chunk XOR tok&15
#pragma unroll
  for (int pass = 0; pass < 2; ++pass) {
    __syncthreads();
    if (wn == pass) {
#pragma unroll
      for (int mi = 0; mi < 2; ++mi)
#pragma unroll
        for (int ni = 0; ni < 4; ++ni) {
          int tok = wm * 32 + 16 * mi + lane16;
          int cc  = (4 * ni + half) ^ (tok & 15);
          *(f32x4*)&Lf[tok * 64 + cc * 4] = acc[mi][ni];
        }
    }
    __syncthreads();
#pragma unroll
    for (int j = 0; j < 4; ++j) {
      int id = j * 256 + tid;             // 0..1023 = [tok][c]
      int tok = id >> 4, c = id & 15;
      int cc = c ^ (tok & 15);
      f32x4 v = *(const f32x4*)&Lf[tok * 64 + cc * 4];
      *(f32x4*)&res[(long)(mt * 64 + tok) * D_ + nt * 128 + pass * 64 + c * 4] = v;
    }
  }
}

// ---------------------------------------------------------------------------
// Copy fp32 result scratch -> d_out (16 MB)  [fallback path only]
// ---------------------------------------------------------------------------
__global__ __launch_bounds__(256) void copy_kernel(const float* __restrict__ src,
                                                   float* __restrict__ dst) {
  long i = ((long)blockIdx.x * 256 + threadIdx.x) * 8;
  *(f32x4*)&dst[i]     = *(const f32x4*)&src[i];
  *(f32x4*)&dst[i + 4] = *(const f32x4*)&src[i + 4];
}

// ---------------------------------------------------------------------------
extern "C" void kernel_launch(void* const* d_in, const int* in_sizes, int n_in,
                              void* d_out, int out_size, void* d_ws, size_t ws_size,
                              hipStream_t stream) {
  const float* x     = (const float*)d_in[0];
  const float* wq_lb = (const float*)d_in[1];
  const float* wk_lb = (const float*)d_in[2];
  const float* wv_lb = (const float*)d_in[3];
  const float* wq_la = (const float*)d_in[4];
  const float* wk_la = (const float*)d_in[5];
  const float* wv_la = (const float*)d_in[6];
  const float* wo    = (const float*)d_in[7];
  float* out = (float*)d_out;

  const size_t per_buf = (size_t)B_ * H_ * NTOK * E_;   // 4M elems (8MB bf16)

  bf16_t* Qb = (bf16_t*)d_ws;
  bf16_t* Kb = Qb + per_buf;
  bf16_t* Vt = Kb + per_buf;

  bf16_t* xb = (bf16_t*)d_out;
  bf16_t* Wb = xb + per_buf;

  const bool direct = ws_size >= (size_t)34 * 1024 * 1024;

  if (direct) {
    bf16_t* Ob  = Vt + per_buf;
    bf16_t* Wob = Ob + per_buf;
    prep_kernel<<<4096, 256, 0, stream>>>(x, wq_lb, wq_la, wk_lb, wk_la,
                                          wv_lb, wv_la, wo, xb, Wb, Wob);
    qkv128_kernel<<<dim3(32, 24), 256, 0, stream>>>(xb, Wb, Qb, Kb, Vt);
    attn_kernel<<<dim3(32, 16, 2), 256, 0, stream>>>(Qb, Kb, Vt, Ob);
    oproj64_kernel<<<dim3(64, 8), 256, 0, stream>>>(Ob, Wob, out);
  } else {
    bf16_t* Wob = Wb + (size_t)3 * 1024 * 1024;
    bf16_t* Ob  = (bf16_t*)d_out;
    float*  res = (float*)d_ws;
    prep_kernel<<<4096, 256, 0, stream>>>(x, wq_lb, wq_la, wk_lb, wk_la,
                                          wv_lb, wv_la, wo, xb, Wb, Wob);
    qkv128_kernel<<<dim3(32, 24), 256, 0, stream>>>(xb, Wb, Qb, Kb, Vt);
    attn_kernel<<<dim3(32, 16, 2), 256, 0, stream>>>(Qb, Kb, Vt, Ob);
    oproj64_kernel<<<dim3(64, 8), 256, 0, stream>>>(Ob, Wob, res);
    copy_kernel<<<2048, 256, 0, stream>>>(res, out);
  }
}